// Round 1
// baseline (352.126 us; speedup 1.0000x reference)
//
#include <hip/hip_runtime.h>
#include <math.h>

// SPP mix (max + mean), levels {1,2,4}, input (32,64,64,512) fp32 channels-last.
// Strategy: single pass computes per-(b, 4x4 bin) max & sum over 16x16 windows
// (reads input exactly once, HBM-bound); tiny second kernel aggregates levels
// 2 and 1 from the 4x4 partials and writes all outputs in reference order.

#define B_ 32
#define HW_ 64
#define C_ 512
#define CVEC 128  // C/4 float4 channel-groups

__device__ __forceinline__ float4 f4max(float4 a, float4 b) {
    return make_float4(fmaxf(a.x, b.x), fmaxf(a.y, b.y),
                       fmaxf(a.z, b.z), fmaxf(a.w, b.w));
}
__device__ __forceinline__ float4 f4add(float4 a, float4 b) {
    return make_float4(a.x + b.x, a.y + b.y, a.z + b.z, a.w + b.w);
}
__device__ __forceinline__ float4 f4mix(float4 m, float4 s, float inv) {
    return make_float4(m.x + s.x * inv, m.y + s.y * inv,
                       m.z + s.z * inv, m.w + s.w * inv);
}

// Kernel 1: one block per (b, bin), bin = br*4+bc over 4x4 grid of 16x16 windows.
// 256 threads = 128 channel-groups x 2 spatial halves (rows 0-7 / 8-15).
__global__ __launch_bounds__(256) void spp_bins_kernel(
    const float4* __restrict__ x,
    float4* __restrict__ maxbuf,
    float4* __restrict__ sumbuf)
{
    const int blk  = blockIdx.x;       // [0, B_*16)
    const int b    = blk >> 4;
    const int bin  = blk & 15;
    const int br   = bin >> 2;
    const int bc   = bin & 3;
    const int tid  = threadIdx.x;
    const int cg   = tid & (CVEC - 1);
    const int half = tid >> 7;

    // float4 index of x[b][br*16][bc*16][4*cg]
    const int base = ((b * HW_ + br * 16) * HW_ + bc * 16) * CVEC + cg;

    float4 mx = make_float4(-INFINITY, -INFINITY, -INFINITY, -INFINITY);
    float4 sm = make_float4(0.f, 0.f, 0.f, 0.f);

    #pragma unroll 8
    for (int k = 0; k < 128; ++k) {
        const int s = (half << 7) + k;   // window-position [0,256)
        const int i = s >> 4;            // window row
        const int j = s & 15;            // window col
        const float4 v = x[base + (i * HW_ + j) * CVEC];
        mx = f4max(mx, v);
        sm = f4add(sm, v);
    }

    __shared__ float4 smax[CVEC];
    __shared__ float4 ssum[CVEC];
    if (half == 1) { smax[cg] = mx; ssum[cg] = sm; }
    __syncthreads();
    if (half == 0) {
        mx = f4max(mx, smax[cg]);
        sm = f4add(sm, ssum[cg]);
        const int o = (b * 16 + bin) * CVEC + cg;
        maxbuf[o] = mx;
        sumbuf[o] = sm;
    }
}

// Kernel 2: per (b, channel-group), read 16 bin partials, emit all 21 outputs.
// Output row per batch: [level1: C][level2: 4C][level4: 16C], element index
// within level p: (pc*p + pr)*C + c  (reference transposes rows/cols).
__global__ __launch_bounds__(256) void spp_agg_kernel(
    const float4* __restrict__ maxbuf,
    const float4* __restrict__ sumbuf,
    float4* __restrict__ out)
{
    const int idx = blockIdx.x * 256 + threadIdx.x;  // [0, B_*CVEC)
    const int b   = idx >> 7;
    const int cg  = idx & (CVEC - 1);

    float4 m[16], s[16];
    #pragma unroll
    for (int bin = 0; bin < 16; ++bin) {
        const int o = (b * 16 + bin) * CVEC + cg;
        m[bin] = maxbuf[o];
        s[bin] = sumbuf[o];
    }

    const int row = b * (21 * CVEC);

    // level 4 (offset 5C = 640 float4): window 16x16 -> mean /256
    #pragma unroll
    for (int br = 0; br < 4; ++br) {
        #pragma unroll
        for (int bc = 0; bc < 4; ++bc) {
            const int bin = br * 4 + bc;
            out[row + 5 * CVEC + (bc * 4 + br) * CVEC + cg] =
                f4mix(m[bin], s[bin], 1.0f / 256.0f);
        }
    }

    // level 2 (offset C = 128 float4): combine 2x2 bins, mean /1024
    float4 m2[4], s2[4];
    #pragma unroll
    for (int pr = 0; pr < 2; ++pr) {
        #pragma unroll
        for (int pc = 0; pc < 2; ++pc) {
            const int b00 = (2 * pr) * 4 + (2 * pc);
            float4 mm = f4max(f4max(m[b00], m[b00 + 1]),
                              f4max(m[b00 + 4], m[b00 + 5]));
            float4 ss = f4add(f4add(s[b00], s[b00 + 1]),
                              f4add(s[b00 + 4], s[b00 + 5]));
            m2[pr * 2 + pc] = mm;
            s2[pr * 2 + pc] = ss;
            out[row + CVEC + (pc * 2 + pr) * CVEC + cg] =
                f4mix(mm, ss, 1.0f / 1024.0f);
        }
    }

    // level 1 (offset 0): combine everything, mean /4096
    float4 mm = f4max(f4max(m2[0], m2[1]), f4max(m2[2], m2[3]));
    float4 ss = f4add(f4add(s2[0], s2[1]), f4add(s2[2], s2[3]));
    out[row + cg] = f4mix(mm, ss, 1.0f / 4096.0f);
}

extern "C" void kernel_launch(void* const* d_in, const int* in_sizes, int n_in,
                              void* d_out, int out_size, void* d_ws, size_t ws_size,
                              hipStream_t stream) {
    const float4* x = (const float4*)d_in[0];
    float* ws = (float*)d_ws;
    float4* maxbuf = (float4*)ws;                        // 32*16*512 floats
    float4* sumbuf = (float4*)(ws + B_ * 16 * C_);       // 32*16*512 floats
    float4* out = (float4*)d_out;

    spp_bins_kernel<<<B_ * 16, 256, 0, stream>>>(x, maxbuf, sumbuf);
    spp_agg_kernel<<<(B_ * CVEC) / 256, 256, 0, stream>>>(maxbuf, sumbuf, out);
}